// Round 15
// baseline (1200.207 us; speedup 1.0000x reference)
//
#include <hip/hip_runtime.h>
#include <hip/hip_bf16.h>

#define N_ROWS 131072
#define DIM    768
#define K_C    2000
#define K_PAD  2048
#define TAU    0.2f
#define LISTCAP 8192

typedef _Float16 f16;
typedef _Float16 f16x4 __attribute__((ext_vector_type(4)));
typedef _Float16 f16x8 __attribute__((ext_vector_type(8)));
typedef float    f32x4 __attribute__((ext_vector_type(4)));

// ---- workspace layout (bytes) ----
#define OFF_CN   6291456    // cn   [2048] f32
#define OFF_XN   6299648    // xn   [131072] f32
#define OFF_PMIN 6823936    // pmin [8][131072] f32
#define OFF_PSEC 15212544   // psec [8][131072] f32
#define OFF_PIDX 23601152   // pidx [8][131072] i32
#define OFF_CNT  31989760   // counter
#define OFF_LIST 31990016   // list [8192] i32
#define OFF_CN64 32022784   // cn64 [2048] f64
#define OFF_XH   32039168   // xh [131072][768] f16

static __device__ __forceinline__ void gload16(const void* g, void* l) {
  __builtin_amdgcn_global_load_lds(
      (const __attribute__((address_space(1))) unsigned int*)g,
      (__attribute__((address_space(3))) unsigned int*)l, 16, 0, 0);
}

// K1a: c_norm, 64 blocks x 8-way d-split (fp32 feeds gate margins only;
// fp64 cn64 for the exact recheck).
__global__ __launch_bounds__(256) void prep_cn(const float* __restrict__ cent,
                                               float* __restrict__ cn,
                                               double* __restrict__ cn64) {
#pragma clang fp contract(off)
  __shared__ float pf[8][32];
  __shared__ double pd[8][32];
  int t = threadIdx.x;
  int kk = t & 31;
  int k = blockIdx.x * 32 + kk;
  int p = t >> 5;
  float s = 0.0f;
  double s64 = 0.0;
  for (int d = p * 96; d < p * 96 + 96; ++d) {
    float c = (k < K_C) ? cent[d * K_C + k] : 0.0f;
    float sq = c * c;
    s = s + sq;
    s64 += (double)c * (double)c;
  }
  pf[p][kk] = s;
  pd[p][kk] = s64;
  __syncthreads();
  if (p == 0) {
    float ss = 0.0f;
    double ss64 = 0.0;
#pragma unroll
    for (int q = 0; q < 8; ++q) {
      ss = ss + pf[q][kk];
      ss64 += pd[q][kk];
    }
    cn[k] = (k < K_C) ? ss : INFINITY;
    cn64[k] = (k < K_C) ? ss64 : (double)INFINITY;
  }
}

// K1b: centroid transpose to f16 via 64x64 LDS tile.
__global__ __launch_bounds__(256) void prep_ct(const float* __restrict__ cent,
                                               f16* __restrict__ cTh) {
  __shared__ float ld[64][65];
  int k0 = blockIdx.x * 64;  // 32 blocks
  int d0 = blockIdx.y * 64;  // 12 blocks
  int tid = threadIdx.x;
#pragma unroll
  for (int it = 0; it < 16; ++it) {
    int idx = it * 256 + tid;
    int dd = idx >> 6, kk = idx & 63;
    int k = k0 + kk;
    ld[dd][kk] = (k < K_C) ? cent[(size_t)(d0 + dd) * K_C + k] : 0.0f;
  }
  __syncthreads();
#pragma unroll
  for (int it = 0; it < 16; ++it) {
    int idx = it * 256 + tid;
    int kk = idx >> 6, dd = idx & 63;
    cTh[(size_t)(k0 + kk) * DIM + d0 + dd] = (f16)ld[dd][kk];
  }
}

// K2: x_norm (numpy FLOAT_pairwise_sum(768) scalar semantics) fused with
// x -> f16.
__global__ __launch_bounds__(256) void xnorm_prepx(const float* __restrict__ x,
                                                   float* __restrict__ xn,
                                                   f16* __restrict__ xh) {
#pragma clang fp contract(off)
  __shared__ __align__(16) float buf[16 * DIM];  // 48 KB, 16 rows
  int row0 = blockIdx.x * 16;
  int tid = threadIdx.x;
  const f32x4* src = (const f32x4*)(x + (size_t)row0 * DIM);
  f32x4* dst = (f32x4*)buf;
#pragma unroll
  for (int c = 0; c < 12; ++c) {
    f32x4 v = src[c * 256 + tid];
    dst[c * 256 + tid] = v;
    f16x4 hv;
#pragma unroll
    for (int j = 0; j < 4; ++j) hv[j] = (f16)v[j];
    *(f16x4*)(xh + (size_t)row0 * DIM + (size_t)(c * 256 + tid) * 4) = hv;
  }
  __syncthreads();
  int w = tid >> 6, lane = tid & 63;
  int b = lane >> 3, j = lane & 7;
#pragma unroll
  for (int rr = 0; rr < 4; ++rr) {
    int r = w * 4 + rr;
    const float* a = buf + r * DIM + 96 * b + j;
    float v0 = a[0];
    float acc = v0 * v0;
#pragma unroll
    for (int t = 1; t < 12; ++t) {
      float q = a[8 * t];
      float s = q * q;
      acc = acc + s;
    }
    float v = acc;
    { float o = __shfl_xor(v, 1);  v = v + o; }
    { float o = __shfl_xor(v, 2);  v = v + o; }
    { float o = __shfl_xor(v, 4);  v = v + o; }
    { float o = __shfl_xor(v, 8);  v = v + o; }
    { float o = __shfl_xor(v, 16); v = v + o; }
    { float o = __shfl_xor(v, 32); v = v + o; }
    if (lane == 0) xn[row0 + r] = v;
  }
}

// K3: f16 MFMA GEMM + fused argmin. 512 threads, 256x256 tile, 8 waves
// (2M x 4N, each 128x64 output -> 12 ds_read : 32 independent MFMA per
// step). r13's PROVEN pipeline verbatim: triple-ring (3 x 32KB slots,
// 96KB, 1 block/CU), vmcnt(4)-BEFORE-barrier (own stage(kt) done ->
// barrier -> everyone's done), stage kt+2 after barrier into the slot
// freed at kt-1, granule swizzle (slot s at row r holds granule
// s^((r>>1)&3); conflicts measured 0 in r13).
// LDS: A slots @0/16384/32768 (256 rows x 64B), B @49152/65536/81920.
#define STAGE5(bufo)                                                           \
  do {                                                                         \
    gload16(pA0, ldsb + (bufo) + (w * 2) * 1024);                              \
    gload16(pA1, ldsb + (bufo) + (w * 2 + 1) * 1024);                          \
    gload16(pB0, ldsb + 49152 + (bufo) + (w * 2) * 1024);                      \
    gload16(pB1, ldsb + 49152 + (bufo) + (w * 2 + 1) * 1024);                  \
    pA0 += 64; pA1 += 64; pB0 += 64; pB1 += 64;                                \
  } while (0)

__global__ __launch_bounds__(512, 1) void kmeans_main(
    const f16* __restrict__ xh, const f16* __restrict__ cTh,
    const float* __restrict__ cn, const float* __restrict__ xn,
    float* __restrict__ pmin, float* __restrict__ psec,
    int* __restrict__ pidx) {
  __shared__ __align__(16) f16 lds[49152];  // 96 KiB
  char* ldsb = (char*)lds;

  int d0 = blockIdx.x;
  int g  = (d0 & 7) * 512 + (d0 >> 3);  // XCD-grouped, 4096 blocks
  int pb = g & 7;    // column panel (256 cols)
  int rb = g >> 3;   // row block (256 rows)

  int tid  = threadIdx.x;
  int w    = tid >> 6;      // 0..7
  int lane = tid & 63;
  int wr   = w >> 2;        // 0..1: row half (128 rows)
  int wc   = w & 3;         // 0..3: col quarter (64 cols)

  int rsel = lane & 15;
  int ksel = lane >> 4;
  int rs = (ksel ^ ((rsel >> 1) & 3)) << 4;  // swizzled granule byte-offset

  // staging: A = 16 chunks (256 rows), B = 16 chunks (256 cols); 1KB chunks
  // of 16 rows x 64B. Wave w stages chunks {2w, 2w+1} of each array.
  int grn = (lane & 3) ^ ((lane >> 3) & 3);  // inverse-swizzled src granule
  const char* pA0 = (const char*)xh +
      ((size_t)(rb * 256 + (w * 2) * 16 + (lane >> 2)) * DIM + grn * 8) * 2;
  const char* pA1 = (const char*)xh +
      ((size_t)(rb * 256 + (w * 2 + 1) * 16 + (lane >> 2)) * DIM + grn * 8) * 2;
  const char* pB0 = (const char*)cTh +
      ((size_t)(pb * 256 + (w * 2) * 16 + (lane >> 2)) * DIM + grn * 8) * 2;
  const char* pB1 = (const char*)cTh +
      ((size_t)(pb * 256 + (w * 2 + 1) * 16 + (lane >> 2)) * DIM + grn * 8) * 2;

  f32x4 acc[8][4] = {};

  STAGE5(0);
  STAGE5(16384);

  int cb = 0;       // current slot offset
  int sb = 32768;   // stage target (slot of kt+2)
#pragma unroll 3
  for (int kt = 0; kt < 24; ++kt) {
    if (kt < 23) {
      asm volatile("s_waitcnt vmcnt(4)" ::: "memory");  // own stage(kt) done;
                                                        // stage(kt+1) in flight
    } else {
      asm volatile("s_waitcnt vmcnt(0)" ::: "memory");
    }
    __builtin_amdgcn_sched_barrier(0);
    __builtin_amdgcn_s_barrier();  // now ALL waves' stage(kt) landed
    __builtin_amdgcn_sched_barrier(0);

    if (kt < 22) STAGE5(sb);  // into slot freed at kt-1

    f16x8 ah[8], bh[4];
    int abase = cb + (wr * 128 + rsel) * 64 + rs;
    int bbase = cb + 49152 + (wc * 64 + rsel) * 64 + rs;
#pragma unroll
    for (int m = 0; m < 8; ++m) ah[m] = *(const f16x8*)(ldsb + abase + m * 1024);
#pragma unroll
    for (int n = 0; n < 4; ++n) bh[n] = *(const f16x8*)(ldsb + bbase + n * 1024);

    // compiler interleaves ds_read completion with MFMA via lgkmcnt(N)
    __builtin_amdgcn_s_setprio(1);
#pragma unroll
    for (int m = 0; m < 8; ++m)
#pragma unroll
      for (int n = 0; n < 4; ++n)
        acc[m][n] = __builtin_amdgcn_mfma_f32_16x16x32_f16(ah[m], bh[n],
                                                           acc[m][n], 0, 0, 0);
    __builtin_amdgcn_s_setprio(0);

    cb = (cb == 32768) ? 0 : cb + 16384;
    sb = (sb == 32768) ? 0 : sb + 16384;
  }

  __syncthreads();  // drain; LDS reused below
  float* lv  = (float*)lds;           // [4][256] by col-wave
  float* lsv = (float*)lds + 1024;    // [4][256]
  int*   li  = (int*)((float*)lds + 2048);  // [4][256]

  int colbase = pb * 256 + wc * 64 + rsel;
  float cnv[4];
#pragma unroll
  for (int n = 0; n < 4; ++n) cnv[n] = cn[colbase + n * 16];
  int g4 = ksel * 4;

#pragma unroll
  for (int m = 0; m < 8; ++m) {
#pragma unroll
    for (int j = 0; j < 4; ++j) {
      int br = wr * 128 + m * 16 + g4 + j;  // block row 0..255
      float xv = xn[rb * 256 + br];
      float v1 = 0.0f, v2 = INFINITY;
      int i1 = 0;
#pragma unroll
      for (int n = 0; n < 4; ++n) {
        float dd = (xv - 2.0f * acc[m][n][j]) + cnv[n];
        int ci = colbase + n * 16;
        if (n == 0) { v1 = dd; i1 = ci; }
        else if (dd < v1) { v2 = v1; v1 = dd; i1 = ci; }
        else { v2 = fminf(v2, dd); }
      }
#pragma unroll
      for (int off = 1; off < 16; off <<= 1) {
        float ov1 = __shfl_xor(v1, off);
        float ov2 = __shfl_xor(v2, off);
        int oi1 = __shfl_xor(i1, off);
        if (ov1 < v1 || (ov1 == v1 && oi1 < i1)) {
          v2 = fminf(v1, ov2); v1 = ov1; i1 = oi1;
        } else {
          v2 = fminf(v2, ov1);
        }
      }
      if ((lane & 15) == 0) {
        lv[wc * 256 + br] = v1;
        lsv[wc * 256 + br] = v2;
        li[wc * 256 + br] = i1;
      }
    }
  }
  __syncthreads();
  if (tid < 256) {
    float v1 = lv[tid], v2 = lsv[tid];
    int i1 = li[tid];
#pragma unroll
    for (int q = 1; q < 4; ++q) {
      float b1 = lv[q * 256 + tid], b2 = lsv[q * 256 + tid];
      int bj = li[q * 256 + tid];
      if (b1 < v1) {             // cols ordered by q: strict < keeps
        v2 = fminf(v1, b2);      // first index on ties
        v1 = b1; i1 = bj;
      } else {
        v2 = fminf(v2, b1);      // b2 >= b1 >= v1: only b1 competes
      }
    }
    size_t o = (size_t)pb * N_ROWS + rb * 256 + tid;
    pmin[o] = v1;
    psec[o] = v2;
    pidx[o] = i1;
  }
}

// K4: merge 8 panel triples; flag ambiguous rows (margin < TAU).
__global__ void merge_detect(const float* __restrict__ pmin,
                             const float* __restrict__ psec,
                             const int* __restrict__ pidx, int* __restrict__ out,
                             int* __restrict__ list, int* __restrict__ counter) {
  int n = blockIdx.x * 256 + threadIdx.x;
  float v1 = INFINITY, v2 = INFINITY;
  int i1 = 0x7fffffff;
  for (int p = 0; p < 8; ++p) {
    float a1 = pmin[(size_t)p * N_ROWS + n];
    float a2 = psec[(size_t)p * N_ROWS + n];
    int aj = pidx[(size_t)p * N_ROWS + n];
    if (a1 < v1 || (a1 == v1 && aj < i1)) {
      v2 = fminf(v1, a2); v1 = a1; i1 = aj;
    } else {
      v2 = fminf(v2, a1);
    }
  }
  out[n] = i1;
  if (v2 - v1 < TAU) {
    int idx = atomicAdd(counter, 1);
    if (idx < LISTCAP) list[idx] = n;
  }
}

// K5: float64 exact recheck, BATCH-4 rows per block; 32 NAMED f64
// accumulators (rule #20).
#define ACCS(R) \
  double a##R##0 = 0, a##R##1 = 0, a##R##2 = 0, a##R##3 = 0, \
         a##R##4 = 0, a##R##5 = 0, a##R##6 = 0, a##R##7 = 0
#define FMAS(R, XV) \
  a##R##0 = fma(XV, c0, a##R##0); a##R##1 = fma(XV, c1, a##R##1); \
  a##R##2 = fma(XV, c2, a##R##2); a##R##3 = fma(XV, c3, a##R##3); \
  a##R##4 = fma(XV, c4, a##R##4); a##R##5 = fma(XV, c5, a##R##5); \
  a##R##6 = fma(XV, c6, a##R##6); a##R##7 = fma(XV, c7, a##R##7)
#define EVAL(R)                                                         \
  {                                                                     \
    double dots[8] = {a##R##0, a##R##1, a##R##2, a##R##3,               \
                      a##R##4, a##R##5, a##R##6, a##R##7};              \
    double bv = (double)INFINITY;                                       \
    int bi = 0x7fffffff;                                                \
    _Pragma("unroll") for (int j = 0; j < 8; ++j) {                     \
      int k = tid + j * 256;                                            \
      if (k < K_C) {                                                    \
        double dd = (xnorms[R] - 2.0 * dots[j]) + cn64[k];              \
        if (dd < bv) { bv = dd; bi = k; }                               \
      }                                                                 \
    }                                                                   \
    rv[tid] = bv; ri[tid] = bi;                                         \
    __syncthreads();                                                    \
    for (int s = 128; s > 0; s >>= 1) {                                 \
      if (tid < s) {                                                    \
        double ov = rv[tid + s];                                        \
        int oi = ri[tid + s];                                           \
        if (ov < rv[tid] || (ov == rv[tid] && oi < ri[tid])) {          \
          rv[tid] = ov; ri[tid] = oi;                                   \
        }                                                               \
      }                                                                 \
      __syncthreads();                                                  \
    }                                                                   \
    if (tid == 0 && (R) < nrows) out[list[b0 + (R)]] = ri[0];           \
    __syncthreads();                                                    \
  }

__global__ __launch_bounds__(256) void exact_recheck64(
    const float* __restrict__ x, const float* __restrict__ cent,
    const double* __restrict__ cn64, const int* __restrict__ list,
    const int* __restrict__ counter, int* __restrict__ out) {
  __shared__ __align__(16) float xrow[4][DIM];  // 12 KB
  __shared__ double rv[256];
  __shared__ int ri[256];
  __shared__ double xnorms[4];
  int cnt = counter[0];
  if (cnt > LISTCAP) cnt = LISTCAP;
  int b0 = blockIdx.x * 4;
  if (b0 >= cnt) return;
  int nrows = cnt - b0;
  if (nrows > 4) nrows = 4;
  int tid = threadIdx.x;
  for (int r = 0; r < 4; ++r) {
    int n = list[b0 + (r < nrows ? r : 0)];
    double part = 0.0;
    for (int d = tid; d < DIM; d += 256) {
      float v = x[(size_t)n * DIM + d];
      xrow[r][d] = v;
      part += (double)v * (double)v;
    }
    rv[tid] = part;
    __syncthreads();
    for (int s = 128; s > 0; s >>= 1) {
      if (tid < s) rv[tid] += rv[tid + s];
      __syncthreads();
    }
    if (tid == 0) xnorms[r] = rv[0];
    __syncthreads();
  }

  int k7 = tid + 1792;
  int k7c = (k7 < K_C) ? k7 : (K_C - 1);
  ACCS(0); ACCS(1); ACCS(2); ACCS(3);
#pragma unroll 2
  for (int d = 0; d < DIM; ++d) {
    const float* cp = cent + (size_t)d * K_C + tid;
    double c0 = cp[0], c1 = cp[256], c2 = cp[512], c3 = cp[768];
    double c4 = cp[1024], c5 = cp[1280], c6 = cp[1536];
    double c7 = cp[k7c - tid];
    double x0 = xrow[0][d], x1 = xrow[1][d];
    double x2 = xrow[2][d], x3 = xrow[3][d];
    FMAS(0, x0); FMAS(1, x1); FMAS(2, x2); FMAS(3, x3);
  }
  EVAL(0) EVAL(1) EVAL(2) EVAL(3)
}

extern "C" void kernel_launch(void* const* d_in, const int* in_sizes, int n_in,
                              void* d_out, int out_size, void* d_ws, size_t ws_size,
                              hipStream_t stream) {
  const float* x = (const float*)d_in[0];
  const float* cent = (const float*)d_in[1];
  char* ws = (char*)d_ws;
  f16* cTh = (f16*)ws;
  float* cn = (float*)(ws + OFF_CN);
  float* xn = (float*)(ws + OFF_XN);
  float* pmin = (float*)(ws + OFF_PMIN);
  float* psec = (float*)(ws + OFF_PSEC);
  int* pidx = (int*)(ws + OFF_PIDX);
  int* counter = (int*)(ws + OFF_CNT);
  int* list = (int*)(ws + OFF_LIST);
  double* cn64 = (double*)(ws + OFF_CN64);
  f16* xh = (f16*)(ws + OFF_XH);

  hipMemsetAsync(counter, 0, 4, stream);
  prep_cn<<<64, 256, 0, stream>>>(cent, cn, cn64);
  prep_ct<<<dim3(32, 12), 256, 0, stream>>>(cent, cTh);
  xnorm_prepx<<<N_ROWS / 16, 256, 0, stream>>>(x, xn, xh);
  kmeans_main<<<4096, 512, 0, stream>>>(xh, cTh, cn, xn, pmin, psec, pidx);
  merge_detect<<<N_ROWS / 256, 256, 0, stream>>>(pmin, psec, pidx, (int*)d_out,
                                                 list, counter);
  exact_recheck64<<<LISTCAP / 4, 256, 0, stream>>>(x, cent, cn64, list, counter,
                                                   (int*)d_out);
}

// Round 16
// 1186.967 us; speedup vs baseline: 1.0112x; 1.0112x over previous
//
#include <hip/hip_runtime.h>
#include <hip/hip_bf16.h>

#define N_ROWS 131072
#define DIM    768
#define K_C    2000
#define K_PAD  2048
#define TAU    0.2f
#define LISTCAP 8192

typedef _Float16 f16;
typedef _Float16 f16x4 __attribute__((ext_vector_type(4)));
typedef _Float16 f16x8 __attribute__((ext_vector_type(8)));
typedef float    f32x4 __attribute__((ext_vector_type(4)));

// ---- workspace layout (bytes) ----
#define OFF_CN   6291456    // cn   [2048] f32
#define OFF_XN   6299648    // xn   [131072] f32
#define OFF_PMIN 6823936    // pmin [16][131072] f32
#define OFF_PSEC 15212544   // psec [16][131072] f32
#define OFF_PIDX 23601152   // pidx [16][131072] i32
#define OFF_CNT  31989760   // counter
#define OFF_LIST 31990016   // list [8192] i32
#define OFF_CN64 32022784   // cn64 [2048] f64
#define OFF_XH   32039168   // xh [131072][768] f16

static __device__ __forceinline__ void gload16(const void* g, void* l) {
  __builtin_amdgcn_global_load_lds(
      (const __attribute__((address_space(1))) unsigned int*)g,
      (__attribute__((address_space(3))) unsigned int*)l, 16, 0, 0);
}

// K1a: c_norm, 64 blocks x 8-way d-split (fp32 feeds gate margins only;
// fp64 cn64 for the exact recheck).
__global__ __launch_bounds__(256) void prep_cn(const float* __restrict__ cent,
                                               float* __restrict__ cn,
                                               double* __restrict__ cn64) {
#pragma clang fp contract(off)
  __shared__ float pf[8][32];
  __shared__ double pd[8][32];
  int t = threadIdx.x;
  int kk = t & 31;
  int k = blockIdx.x * 32 + kk;
  int p = t >> 5;
  float s = 0.0f;
  double s64 = 0.0;
  for (int d = p * 96; d < p * 96 + 96; ++d) {
    float c = (k < K_C) ? cent[d * K_C + k] : 0.0f;
    float sq = c * c;
    s = s + sq;
    s64 += (double)c * (double)c;
  }
  pf[p][kk] = s;
  pd[p][kk] = s64;
  __syncthreads();
  if (p == 0) {
    float ss = 0.0f;
    double ss64 = 0.0;
#pragma unroll
    for (int q = 0; q < 8; ++q) {
      ss = ss + pf[q][kk];
      ss64 += pd[q][kk];
    }
    cn[k] = (k < K_C) ? ss : INFINITY;
    cn64[k] = (k < K_C) ? ss64 : (double)INFINITY;
  }
}

// K1b: centroid transpose to f16 via 64x64 LDS tile.
__global__ __launch_bounds__(256) void prep_ct(const float* __restrict__ cent,
                                               f16* __restrict__ cTh) {
  __shared__ float ld[64][65];
  int k0 = blockIdx.x * 64;  // 32 blocks
  int d0 = blockIdx.y * 64;  // 12 blocks
  int tid = threadIdx.x;
#pragma unroll
  for (int it = 0; it < 16; ++it) {
    int idx = it * 256 + tid;
    int dd = idx >> 6, kk = idx & 63;
    int k = k0 + kk;
    ld[dd][kk] = (k < K_C) ? cent[(size_t)(d0 + dd) * K_C + k] : 0.0f;
  }
  __syncthreads();
#pragma unroll
  for (int it = 0; it < 16; ++it) {
    int idx = it * 256 + tid;
    int kk = idx >> 6, dd = idx & 63;
    cTh[(size_t)(k0 + kk) * DIM + d0 + dd] = (f16)ld[dd][kk];
  }
}

// K2: x_norm (numpy FLOAT_pairwise_sum(768) scalar semantics) fused with
// x -> f16.
__global__ __launch_bounds__(256) void xnorm_prepx(const float* __restrict__ x,
                                                   float* __restrict__ xn,
                                                   f16* __restrict__ xh) {
#pragma clang fp contract(off)
  __shared__ __align__(16) float buf[16 * DIM];  // 48 KB, 16 rows
  int row0 = blockIdx.x * 16;
  int tid = threadIdx.x;
  const f32x4* src = (const f32x4*)(x + (size_t)row0 * DIM);
  f32x4* dst = (f32x4*)buf;
#pragma unroll
  for (int c = 0; c < 12; ++c) {
    f32x4 v = src[c * 256 + tid];
    dst[c * 256 + tid] = v;
    f16x4 hv;
#pragma unroll
    for (int j = 0; j < 4; ++j) hv[j] = (f16)v[j];
    *(f16x4*)(xh + (size_t)row0 * DIM + (size_t)(c * 256 + tid) * 4) = hv;
  }
  __syncthreads();
  int w = tid >> 6, lane = tid & 63;
  int b = lane >> 3, j = lane & 7;
#pragma unroll
  for (int rr = 0; rr < 4; ++rr) {
    int r = w * 4 + rr;
    const float* a = buf + r * DIM + 96 * b + j;
    float v0 = a[0];
    float acc = v0 * v0;
#pragma unroll
    for (int t = 1; t < 12; ++t) {
      float q = a[8 * t];
      float s = q * q;
      acc = acc + s;
    }
    float v = acc;
    { float o = __shfl_xor(v, 1);  v = v + o; }
    { float o = __shfl_xor(v, 2);  v = v + o; }
    { float o = __shfl_xor(v, 4);  v = v + o; }
    { float o = __shfl_xor(v, 8);  v = v + o; }
    { float o = __shfl_xor(v, 16); v = v + o; }
    { float o = __shfl_xor(v, 32); v = v + o; }
    if (lane == 0) xn[row0 + r] = v;
  }
}

// K3: f16 MFMA GEMM + fused argmin — r13 PROVEN BEST (661us, MfmaUtil 29%,
// conflicts 0). Triple-buffered BK=32, one barrier/step, counted vmcnt(4),
// granule swizzle (slot s at row r holds granule s^((r>>1)&3)), hoisted
// stage pointers, 48KB LDS -> 3 blocks/CU. r14/r15 showed bigger tiles
// lose more from occupancy than they gain from read:MFMA ratio.
#define STAGE3(bufo)                                                           \
  do {                                                                         \
    gload16(pA0, ldsb + (bufo) + c0 * 1024);                                   \
    gload16(pA1, ldsb + (bufo) + c1 * 1024);                                   \
    gload16(pB0, ldsb + 24576 + (bufo) + c0 * 1024);                           \
    gload16(pB1, ldsb + 24576 + (bufo) + c1 * 1024);                           \
    pA0 += 64; pA1 += 64; pB0 += 64; pB1 += 64;                                \
  } while (0)

__global__ __launch_bounds__(256, 3) void kmeans_main(
    const f16* __restrict__ xh, const f16* __restrict__ cTh,
    const float* __restrict__ cn, const float* __restrict__ xn,
    float* __restrict__ pmin, float* __restrict__ psec,
    int* __restrict__ pidx) {
  __shared__ __align__(16) f16 lds[24576];  // 48 KiB
  char* ldsb = (char*)lds;

  int d0 = blockIdx.x;
  int g  = (d0 & 7) * 2048 + (d0 >> 3);  // XCD-grouped
  int pb = g & 15;
  int rb = g >> 4;

  int tid  = threadIdx.x;
  int w    = tid >> 6;
  int lane = tid & 63;
  int wrow = (w >> 1) * 64;
  int wcol = (w & 1) * 64;

  int rsel = lane & 15;
  int ksel = lane >> 4;
  int rs = (ksel ^ ((rsel >> 1) & 3)) << 4;  // swizzled granule byte-offset

  // staging constants: chunk = 1 KB = 16 rows x 64 B; this wave's chunks
  int c0 = w * 2, c1 = w * 2 + 1;
  int grn = (lane & 3) ^ ((lane >> 3) & 3);  // inverse-swizzled src granule
  const char* pA0 = (const char*)xh +
      ((size_t)(rb * 128 + c0 * 16 + (lane >> 2)) * DIM + grn * 8) * 2;
  const char* pA1 = (const char*)xh +
      ((size_t)(rb * 128 + c1 * 16 + (lane >> 2)) * DIM + grn * 8) * 2;
  const char* pB0 = (const char*)cTh +
      ((size_t)(pb * 128 + c0 * 16 + (lane >> 2)) * DIM + grn * 8) * 2;
  const char* pB1 = (const char*)cTh +
      ((size_t)(pb * 128 + c1 * 16 + (lane >> 2)) * DIM + grn * 8) * 2;

  f32x4 acc[4][4] = {};

  STAGE3(0);
  STAGE3(8192);

  int cb = 0;       // current buffer offset
  int sb = 16384;   // stage target (buffer of kt+2)
#pragma unroll 3
  for (int kt = 0; kt < 24; ++kt) {
    if (kt < 23) {
      asm volatile("s_waitcnt vmcnt(4)" ::: "memory");  // tile kt landed;
                                                        // kt+1 stays in flight
    } else {
      asm volatile("s_waitcnt vmcnt(0)" ::: "memory");
    }
    __builtin_amdgcn_sched_barrier(0);
    __builtin_amdgcn_s_barrier();
    __builtin_amdgcn_sched_barrier(0);

    if (kt < 22) STAGE3(sb);  // into buffer freed at kt-1

    f16x8 ah[4], bh[4];
    int abase = cb + (wrow + rsel) * 64 + rs;
    int bbase = cb + 24576 + (wcol + rsel) * 64 + rs;
#pragma unroll
    for (int m = 0; m < 4; ++m) ah[m] = *(const f16x8*)(ldsb + abase + m * 1024);
#pragma unroll
    for (int n = 0; n < 4; ++n) bh[n] = *(const f16x8*)(ldsb + bbase + n * 1024);

    // no manual lgkmcnt wall: compiler interleaves ds_read completion
    // with the MFMA chain via fine-grained lgkmcnt(N)
    __builtin_amdgcn_s_setprio(1);
#pragma unroll
    for (int m = 0; m < 4; ++m)
#pragma unroll
      for (int n = 0; n < 4; ++n)
        acc[m][n] = __builtin_amdgcn_mfma_f32_16x16x32_f16(ah[m], bh[n],
                                                           acc[m][n], 0, 0, 0);
    __builtin_amdgcn_s_setprio(0);

    cb = (cb == 16384) ? 0 : cb + 8192;
    sb = (sb == 16384) ? 0 : sb + 8192;
  }

  __syncthreads();  // drain; LDS reused below
  float* lv = (float*)lds;                 // [2][128]
  float* lsv = (float*)lds + 256;          // [2][128]
  int*   li = (int*)((float*)lds + 512);   // [2][128]

  int colbase = pb * 128 + wcol + rsel;
  float cnv[4];
#pragma unroll
  for (int n = 0; n < 4; ++n) cnv[n] = cn[colbase + n * 16];
  int g4 = ksel * 4;

#pragma unroll
  for (int m = 0; m < 4; ++m) {
#pragma unroll
    for (int j = 0; j < 4; ++j) {
      int trow = wrow + m * 16 + g4 + j;
      float xv = xn[rb * 128 + trow];
      float v1 = 0.0f, v2 = INFINITY;
      int i1 = 0;
#pragma unroll
      for (int n = 0; n < 4; ++n) {
        float dd = (xv - 2.0f * acc[m][n][j]) + cnv[n];
        int ci = colbase + n * 16;
        if (n == 0) { v1 = dd; i1 = ci; }
        else if (dd < v1) { v2 = v1; v1 = dd; i1 = ci; }
        else { v2 = fminf(v2, dd); }
      }
#pragma unroll
      for (int off = 1; off < 16; off <<= 1) {
        float ov1 = __shfl_xor(v1, off);
        float ov2 = __shfl_xor(v2, off);
        int oi1 = __shfl_xor(i1, off);
        if (ov1 < v1 || (ov1 == v1 && oi1 < i1)) {
          v2 = fminf(v1, ov2); v1 = ov1; i1 = oi1;
        } else {
          v2 = fminf(v2, ov1);
        }
      }
      if ((lane & 15) == 0) {
        lv[(w & 1) * 128 + trow] = v1;
        lsv[(w & 1) * 128 + trow] = v2;
        li[(w & 1) * 128 + trow] = i1;
      }
    }
  }
  __syncthreads();
  if (tid < 128) {
    float a1 = lv[tid], a2 = lsv[tid];
    int aj = li[tid];
    float b1 = lv[128 + tid], b2 = lsv[128 + tid];
    int bj = li[128 + tid];
    float v1, v2; int i1;
    if (b1 < a1 || (b1 == a1 && bj < aj)) { v1 = b1; i1 = bj; v2 = fminf(b2, a1); }
    else { v1 = a1; i1 = aj; v2 = fminf(a2, b1); }
    size_t o = (size_t)pb * N_ROWS + rb * 128 + tid;
    pmin[o] = v1;
    psec[o] = v2;
    pidx[o] = i1;
  }
}

// K4: merge 16 panel triples; flag ambiguous rows (margin < TAU).
__global__ void merge_detect(const float* __restrict__ pmin,
                             const float* __restrict__ psec,
                             const int* __restrict__ pidx, int* __restrict__ out,
                             int* __restrict__ list, int* __restrict__ counter) {
  int n = blockIdx.x * 256 + threadIdx.x;
  float v1 = INFINITY, v2 = INFINITY;
  int i1 = 0x7fffffff;
  for (int p = 0; p < 16; ++p) {
    float a1 = pmin[(size_t)p * N_ROWS + n];
    float a2 = psec[(size_t)p * N_ROWS + n];
    int aj = pidx[(size_t)p * N_ROWS + n];
    if (a1 < v1 || (a1 == v1 && aj < i1)) {
      v2 = fminf(v1, a2); v1 = a1; i1 = aj;
    } else {
      v2 = fminf(v2, a1);
    }
  }
  out[n] = i1;
  if (v2 - v1 < TAU) {
    int idx = atomicAdd(counter, 1);
    if (idx < LISTCAP) list[idx] = n;
  }
}

// K5: float64 exact recheck, BATCH-8 rows per block (cent read once per 8
// rows: L2/L3 traffic halves vs batch-4, which was ~200us = #2 kernel).
// 64 NAMED f64 accumulators (rule #20: named scalars stay in VGPRs).
#define ACCS(R) \
  double a##R##0 = 0, a##R##1 = 0, a##R##2 = 0, a##R##3 = 0, \
         a##R##4 = 0, a##R##5 = 0, a##R##6 = 0, a##R##7 = 0
#define FMAS(R, XV) \
  a##R##0 = fma(XV, c0, a##R##0); a##R##1 = fma(XV, c1, a##R##1); \
  a##R##2 = fma(XV, c2, a##R##2); a##R##3 = fma(XV, c3, a##R##3); \
  a##R##4 = fma(XV, c4, a##R##4); a##R##5 = fma(XV, c5, a##R##5); \
  a##R##6 = fma(XV, c6, a##R##6); a##R##7 = fma(XV, c7, a##R##7)
#define EVAL(R)                                                         \
  {                                                                     \
    double dots[8] = {a##R##0, a##R##1, a##R##2, a##R##3,               \
                      a##R##4, a##R##5, a##R##6, a##R##7};              \
    double bv = (double)INFINITY;                                       \
    int bi = 0x7fffffff;                                                \
    _Pragma("unroll") for (int j = 0; j < 8; ++j) {                     \
      int k = tid + j * 256;                                            \
      if (k < K_C) {                                                    \
        double dd = (xnorms[R] - 2.0 * dots[j]) + cn64[k];              \
        if (dd < bv) { bv = dd; bi = k; }                               \
      }                                                                 \
    }                                                                   \
    rv[tid] = bv; ri[tid] = bi;                                         \
    __syncthreads();                                                    \
    for (int s = 128; s > 0; s >>= 1) {                                 \
      if (tid < s) {                                                    \
        double ov = rv[tid + s];                                        \
        int oi = ri[tid + s];                                           \
        if (ov < rv[tid] || (ov == rv[tid] && oi < ri[tid])) {          \
          rv[tid] = ov; ri[tid] = oi;                                   \
        }                                                               \
      }                                                                 \
      __syncthreads();                                                  \
    }                                                                   \
    if (tid == 0 && (R) < nrows) out[list[b0 + (R)]] = ri[0];           \
    __syncthreads();                                                    \
  }

__global__ __launch_bounds__(256) void exact_recheck64(
    const float* __restrict__ x, const float* __restrict__ cent,
    const double* __restrict__ cn64, const int* __restrict__ list,
    const int* __restrict__ counter, int* __restrict__ out) {
  __shared__ __align__(16) float xrow[8][DIM];  // 24 KB
  __shared__ double rv[256];
  __shared__ int ri[256];
  __shared__ double xnorms[8];
  int cnt = counter[0];
  if (cnt > LISTCAP) cnt = LISTCAP;
  int b0 = blockIdx.x * 8;
  if (b0 >= cnt) return;
  int nrows = cnt - b0;
  if (nrows > 8) nrows = 8;
  int tid = threadIdx.x;
  for (int r = 0; r < 8; ++r) {
    int n = list[b0 + (r < nrows ? r : 0)];
    double part = 0.0;
    for (int d = tid; d < DIM; d += 256) {
      float v = x[(size_t)n * DIM + d];
      xrow[r][d] = v;
      part += (double)v * (double)v;
    }
    rv[tid] = part;
    __syncthreads();
    for (int s = 128; s > 0; s >>= 1) {
      if (tid < s) rv[tid] += rv[tid + s];
      __syncthreads();
    }
    if (tid == 0) xnorms[r] = rv[0];
    __syncthreads();
  }

  int k7 = tid + 1792;
  int k7c = (k7 < K_C) ? k7 : (K_C - 1);
  ACCS(0); ACCS(1); ACCS(2); ACCS(3);
  ACCS(4); ACCS(5); ACCS(6); ACCS(7);
  for (int d = 0; d < DIM; ++d) {
    const float* cp = cent + (size_t)d * K_C + tid;
    double c0 = cp[0], c1 = cp[256], c2 = cp[512], c3 = cp[768];
    double c4 = cp[1024], c5 = cp[1280], c6 = cp[1536];
    double c7 = cp[k7c - tid];
    double x0 = xrow[0][d], x1 = xrow[1][d];
    double x2 = xrow[2][d], x3 = xrow[3][d];
    double x4 = xrow[4][d], x5 = xrow[5][d];
    double x6 = xrow[6][d], x7 = xrow[7][d];
    FMAS(0, x0); FMAS(1, x1); FMAS(2, x2); FMAS(3, x3);
    FMAS(4, x4); FMAS(5, x5); FMAS(6, x6); FMAS(7, x7);
  }
  EVAL(0) EVAL(1) EVAL(2) EVAL(3)
  EVAL(4) EVAL(5) EVAL(6) EVAL(7)
}

extern "C" void kernel_launch(void* const* d_in, const int* in_sizes, int n_in,
                              void* d_out, int out_size, void* d_ws, size_t ws_size,
                              hipStream_t stream) {
  const float* x = (const float*)d_in[0];
  const float* cent = (const float*)d_in[1];
  char* ws = (char*)d_ws;
  f16* cTh = (f16*)ws;
  float* cn = (float*)(ws + OFF_CN);
  float* xn = (float*)(ws + OFF_XN);
  float* pmin = (float*)(ws + OFF_PMIN);
  float* psec = (float*)(ws + OFF_PSEC);
  int* pidx = (int*)(ws + OFF_PIDX);
  int* counter = (int*)(ws + OFF_CNT);
  int* list = (int*)(ws + OFF_LIST);
  double* cn64 = (double*)(ws + OFF_CN64);
  f16* xh = (f16*)(ws + OFF_XH);

  hipMemsetAsync(counter, 0, 4, stream);
  prep_cn<<<64, 256, 0, stream>>>(cent, cn, cn64);
  prep_ct<<<dim3(32, 12), 256, 0, stream>>>(cent, cTh);
  xnorm_prepx<<<N_ROWS / 16, 256, 0, stream>>>(x, xn, xh);
  kmeans_main<<<16384, 256, 0, stream>>>(xh, cTh, cn, xn, pmin, psec, pidx);
  merge_detect<<<N_ROWS / 256, 256, 0, stream>>>(pmin, psec, pidx, (int*)d_out,
                                                 list, counter);
  exact_recheck64<<<LISTCAP / 8, 256, 0, stream>>>(x, cent, cn64, list, counter,
                                                   (int*)d_out);
}

// Round 17
// 1037.863 us; speedup vs baseline: 1.1564x; 1.1437x over previous
//
#include <hip/hip_runtime.h>
#include <hip/hip_bf16.h>

#define N_ROWS 131072
#define DIM    768
#define K_C    2000
#define K_PAD  2048
#define TAU    0.2f
#define LISTCAP 8192

typedef _Float16 f16;
typedef _Float16 f16x4 __attribute__((ext_vector_type(4)));
typedef _Float16 f16x8 __attribute__((ext_vector_type(8)));
typedef float    f32x4 __attribute__((ext_vector_type(4)));

// ---- workspace layout (bytes) ----
#define OFF_CN   6291456    // cn   [2048] f32
#define OFF_XN   6299648    // xn   [131072] f32
#define OFF_PMIN 6823936    // pmin [16][131072] f32
#define OFF_PSEC 15212544   // psec [16][131072] f32
#define OFF_PIDX 23601152   // pidx [16][131072] i32
#define OFF_CNT  31989760   // counter
#define OFF_LIST 31990016   // list [8192] i32
#define OFF_CN64 32022784   // cn64 [2048] f64
#define OFF_XH   32039168   // xh [131072][768] f16

static __device__ __forceinline__ void gload16(const void* g, void* l) {
  __builtin_amdgcn_global_load_lds(
      (const __attribute__((address_space(1))) unsigned int*)g,
      (__attribute__((address_space(3))) unsigned int*)l, 16, 0, 0);
}

// K1a: c_norm, 64 blocks x 8-way d-split (fp32 feeds gate margins only;
// fp64 cn64 for the exact recheck).
__global__ __launch_bounds__(256) void prep_cn(const float* __restrict__ cent,
                                               float* __restrict__ cn,
                                               double* __restrict__ cn64) {
#pragma clang fp contract(off)
  __shared__ float pf[8][32];
  __shared__ double pd[8][32];
  int t = threadIdx.x;
  int kk = t & 31;
  int k = blockIdx.x * 32 + kk;
  int p = t >> 5;
  float s = 0.0f;
  double s64 = 0.0;
  for (int d = p * 96; d < p * 96 + 96; ++d) {
    float c = (k < K_C) ? cent[d * K_C + k] : 0.0f;
    float sq = c * c;
    s = s + sq;
    s64 += (double)c * (double)c;
  }
  pf[p][kk] = s;
  pd[p][kk] = s64;
  __syncthreads();
  if (p == 0) {
    float ss = 0.0f;
    double ss64 = 0.0;
#pragma unroll
    for (int q = 0; q < 8; ++q) {
      ss = ss + pf[q][kk];
      ss64 += pd[q][kk];
    }
    cn[k] = (k < K_C) ? ss : INFINITY;
    cn64[k] = (k < K_C) ? ss64 : (double)INFINITY;
  }
}

// K1b: centroid transpose to f16 via 64x64 LDS tile.
__global__ __launch_bounds__(256) void prep_ct(const float* __restrict__ cent,
                                               f16* __restrict__ cTh) {
  __shared__ float ld[64][65];
  int k0 = blockIdx.x * 64;  // 32 blocks
  int d0 = blockIdx.y * 64;  // 12 blocks
  int tid = threadIdx.x;
#pragma unroll
  for (int it = 0; it < 16; ++it) {
    int idx = it * 256 + tid;
    int dd = idx >> 6, kk = idx & 63;
    int k = k0 + kk;
    ld[dd][kk] = (k < K_C) ? cent[(size_t)(d0 + dd) * K_C + k] : 0.0f;
  }
  __syncthreads();
#pragma unroll
  for (int it = 0; it < 16; ++it) {
    int idx = it * 256 + tid;
    int kk = idx >> 6, dd = idx & 63;
    cTh[(size_t)(k0 + kk) * DIM + d0 + dd] = (f16)ld[dd][kk];
  }
}

// K2: x_norm (numpy FLOAT_pairwise_sum(768) scalar semantics) fused with
// x -> f16.
__global__ __launch_bounds__(256) void xnorm_prepx(const float* __restrict__ x,
                                                   float* __restrict__ xn,
                                                   f16* __restrict__ xh) {
#pragma clang fp contract(off)
  __shared__ __align__(16) float buf[16 * DIM];  // 48 KB, 16 rows
  int row0 = blockIdx.x * 16;
  int tid = threadIdx.x;
  const f32x4* src = (const f32x4*)(x + (size_t)row0 * DIM);
  f32x4* dst = (f32x4*)buf;
#pragma unroll
  for (int c = 0; c < 12; ++c) {
    f32x4 v = src[c * 256 + tid];
    dst[c * 256 + tid] = v;
    f16x4 hv;
#pragma unroll
    for (int j = 0; j < 4; ++j) hv[j] = (f16)v[j];
    *(f16x4*)(xh + (size_t)row0 * DIM + (size_t)(c * 256 + tid) * 4) = hv;
  }
  __syncthreads();
  int w = tid >> 6, lane = tid & 63;
  int b = lane >> 3, j = lane & 7;
#pragma unroll
  for (int rr = 0; rr < 4; ++rr) {
    int r = w * 4 + rr;
    const float* a = buf + r * DIM + 96 * b + j;
    float v0 = a[0];
    float acc = v0 * v0;
#pragma unroll
    for (int t = 1; t < 12; ++t) {
      float q = a[8 * t];
      float s = q * q;
      acc = acc + s;
    }
    float v = acc;
    { float o = __shfl_xor(v, 1);  v = v + o; }
    { float o = __shfl_xor(v, 2);  v = v + o; }
    { float o = __shfl_xor(v, 4);  v = v + o; }
    { float o = __shfl_xor(v, 8);  v = v + o; }
    { float o = __shfl_xor(v, 16); v = v + o; }
    { float o = __shfl_xor(v, 32); v = v + o; }
    if (lane == 0) xn[row0 + r] = v;
  }
}

// K3: f16 MFMA GEMM + fused argmin — r13 PROVEN BEST (reproduced r16:
// 668us, MfmaUtil 28, conflicts 0). Triple-buffered BK=32, one barrier
// per step, counted vmcnt(4), granule swizzle (slot s at row r holds
// granule s^((r>>1)&3)), hoisted stage pointers, 48KB LDS -> 3 blocks/CU.
#define STAGE3(bufo)                                                           \
  do {                                                                         \
    gload16(pA0, ldsb + (bufo) + c0 * 1024);                                   \
    gload16(pA1, ldsb + (bufo) + c1 * 1024);                                   \
    gload16(pB0, ldsb + 24576 + (bufo) + c0 * 1024);                           \
    gload16(pB1, ldsb + 24576 + (bufo) + c1 * 1024);                           \
    pA0 += 64; pA1 += 64; pB0 += 64; pB1 += 64;                                \
  } while (0)

__global__ __launch_bounds__(256, 3) void kmeans_main(
    const f16* __restrict__ xh, const f16* __restrict__ cTh,
    const float* __restrict__ cn, const float* __restrict__ xn,
    float* __restrict__ pmin, float* __restrict__ psec,
    int* __restrict__ pidx) {
  __shared__ __align__(16) f16 lds[24576];  // 48 KiB
  char* ldsb = (char*)lds;

  int d0 = blockIdx.x;
  int g  = (d0 & 7) * 2048 + (d0 >> 3);  // XCD-grouped
  int pb = g & 15;
  int rb = g >> 4;

  int tid  = threadIdx.x;
  int w    = tid >> 6;
  int lane = tid & 63;
  int wrow = (w >> 1) * 64;
  int wcol = (w & 1) * 64;

  int rsel = lane & 15;
  int ksel = lane >> 4;
  int rs = (ksel ^ ((rsel >> 1) & 3)) << 4;  // swizzled granule byte-offset

  // staging constants: chunk = 1 KB = 16 rows x 64 B; this wave's chunks
  int c0 = w * 2, c1 = w * 2 + 1;
  int grn = (lane & 3) ^ ((lane >> 3) & 3);  // inverse-swizzled src granule
  const char* pA0 = (const char*)xh +
      ((size_t)(rb * 128 + c0 * 16 + (lane >> 2)) * DIM + grn * 8) * 2;
  const char* pA1 = (const char*)xh +
      ((size_t)(rb * 128 + c1 * 16 + (lane >> 2)) * DIM + grn * 8) * 2;
  const char* pB0 = (const char*)cTh +
      ((size_t)(pb * 128 + c0 * 16 + (lane >> 2)) * DIM + grn * 8) * 2;
  const char* pB1 = (const char*)cTh +
      ((size_t)(pb * 128 + c1 * 16 + (lane >> 2)) * DIM + grn * 8) * 2;

  f32x4 acc[4][4] = {};

  STAGE3(0);
  STAGE3(8192);

  int cb = 0;       // current buffer offset
  int sb = 16384;   // stage target (buffer of kt+2)
#pragma unroll 3
  for (int kt = 0; kt < 24; ++kt) {
    if (kt < 23) {
      asm volatile("s_waitcnt vmcnt(4)" ::: "memory");  // tile kt landed;
                                                        // kt+1 stays in flight
    } else {
      asm volatile("s_waitcnt vmcnt(0)" ::: "memory");
    }
    __builtin_amdgcn_sched_barrier(0);
    __builtin_amdgcn_s_barrier();
    __builtin_amdgcn_sched_barrier(0);

    if (kt < 22) STAGE3(sb);  // into buffer freed at kt-1

    f16x8 ah[4], bh[4];
    int abase = cb + (wrow + rsel) * 64 + rs;
    int bbase = cb + 24576 + (wcol + rsel) * 64 + rs;
#pragma unroll
    for (int m = 0; m < 4; ++m) ah[m] = *(const f16x8*)(ldsb + abase + m * 1024);
#pragma unroll
    for (int n = 0; n < 4; ++n) bh[n] = *(const f16x8*)(ldsb + bbase + n * 1024);

    // no manual lgkmcnt wall: compiler interleaves ds_read completion
    // with the MFMA chain via fine-grained lgkmcnt(N)
    __builtin_amdgcn_s_setprio(1);
#pragma unroll
    for (int m = 0; m < 4; ++m)
#pragma unroll
      for (int n = 0; n < 4; ++n)
        acc[m][n] = __builtin_amdgcn_mfma_f32_16x16x32_f16(ah[m], bh[n],
                                                           acc[m][n], 0, 0, 0);
    __builtin_amdgcn_s_setprio(0);

    cb = (cb == 16384) ? 0 : cb + 8192;
    sb = (sb == 16384) ? 0 : sb + 8192;
  }

  __syncthreads();  // drain; LDS reused below
  float* lv = (float*)lds;                 // [2][128]
  float* lsv = (float*)lds + 256;          // [2][128]
  int*   li = (int*)((float*)lds + 512);   // [2][128]

  int colbase = pb * 128 + wcol + rsel;
  float cnv[4];
#pragma unroll
  for (int n = 0; n < 4; ++n) cnv[n] = cn[colbase + n * 16];
  int g4 = ksel * 4;

#pragma unroll
  for (int m = 0; m < 4; ++m) {
#pragma unroll
    for (int j = 0; j < 4; ++j) {
      int trow = wrow + m * 16 + g4 + j;
      float xv = xn[rb * 128 + trow];
      float v1 = 0.0f, v2 = INFINITY;
      int i1 = 0;
#pragma unroll
      for (int n = 0; n < 4; ++n) {
        float dd = (xv - 2.0f * acc[m][n][j]) + cnv[n];
        int ci = colbase + n * 16;
        if (n == 0) { v1 = dd; i1 = ci; }
        else if (dd < v1) { v2 = v1; v1 = dd; i1 = ci; }
        else { v2 = fminf(v2, dd); }
      }
#pragma unroll
      for (int off = 1; off < 16; off <<= 1) {
        float ov1 = __shfl_xor(v1, off);
        float ov2 = __shfl_xor(v2, off);
        int oi1 = __shfl_xor(i1, off);
        if (ov1 < v1 || (ov1 == v1 && oi1 < i1)) {
          v2 = fminf(v1, ov2); v1 = ov1; i1 = oi1;
        } else {
          v2 = fminf(v2, ov1);
        }
      }
      if ((lane & 15) == 0) {
        lv[(w & 1) * 128 + trow] = v1;
        lsv[(w & 1) * 128 + trow] = v2;
        li[(w & 1) * 128 + trow] = i1;
      }
    }
  }
  __syncthreads();
  if (tid < 128) {
    float a1 = lv[tid], a2 = lsv[tid];
    int aj = li[tid];
    float b1 = lv[128 + tid], b2 = lsv[128 + tid];
    int bj = li[128 + tid];
    float v1, v2; int i1;
    if (b1 < a1 || (b1 == a1 && bj < aj)) { v1 = b1; i1 = bj; v2 = fminf(b2, a1); }
    else { v1 = a1; i1 = aj; v2 = fminf(a2, b1); }
    size_t o = (size_t)pb * N_ROWS + rb * 128 + tid;
    pmin[o] = v1;
    psec[o] = v2;
    pidx[o] = i1;
  }
}

// K4: merge 16 panel triples; flag ambiguous rows (margin < TAU).
__global__ void merge_detect(const float* __restrict__ pmin,
                             const float* __restrict__ psec,
                             const int* __restrict__ pidx, int* __restrict__ out,
                             int* __restrict__ list, int* __restrict__ counter) {
  int n = blockIdx.x * 256 + threadIdx.x;
  float v1 = INFINITY, v2 = INFINITY;
  int i1 = 0x7fffffff;
  for (int p = 0; p < 16; ++p) {
    float a1 = pmin[(size_t)p * N_ROWS + n];
    float a2 = psec[(size_t)p * N_ROWS + n];
    int aj = pidx[(size_t)p * N_ROWS + n];
    if (a1 < v1 || (a1 == v1 && aj < i1)) {
      v2 = fminf(v1, a2); v1 = a1; i1 = aj;
    } else {
      v2 = fminf(v2, a1);
    }
  }
  out[n] = i1;
  if (v2 - v1 < TAU) {
    int idx = atomicAdd(counter, 1);
    if (idx < LISTCAP) list[idx] = n;
  }
}

// K5: float64 exact recheck, BATCH-2 rows per block. r16 lesson: this
// kernel is f64-COMPUTE-bound with a load-balance tail, not L2-bound —
// batch-8 (213 blocks) regressed; batch-2 gives ~850 blocks (~3.3/CU)
// for fine-grained balance. 16 NAMED f64 accumulators (rule #20).
#define ACCS(R) \
  double a##R##0 = 0, a##R##1 = 0, a##R##2 = 0, a##R##3 = 0, \
         a##R##4 = 0, a##R##5 = 0, a##R##6 = 0, a##R##7 = 0
#define FMAS(R, XV) \
  a##R##0 = fma(XV, c0, a##R##0); a##R##1 = fma(XV, c1, a##R##1); \
  a##R##2 = fma(XV, c2, a##R##2); a##R##3 = fma(XV, c3, a##R##3); \
  a##R##4 = fma(XV, c4, a##R##4); a##R##5 = fma(XV, c5, a##R##5); \
  a##R##6 = fma(XV, c6, a##R##6); a##R##7 = fma(XV, c7, a##R##7)
#define EVAL(R)                                                         \
  {                                                                     \
    double dots[8] = {a##R##0, a##R##1, a##R##2, a##R##3,               \
                      a##R##4, a##R##5, a##R##6, a##R##7};              \
    double bv = (double)INFINITY;                                       \
    int bi = 0x7fffffff;                                                \
    _Pragma("unroll") for (int j = 0; j < 8; ++j) {                     \
      int k = tid + j * 256;                                            \
      if (k < K_C) {                                                    \
        double dd = (xnorms[R] - 2.0 * dots[j]) + cn64[k];              \
        if (dd < bv) { bv = dd; bi = k; }                               \
      }                                                                 \
    }                                                                   \
    rv[tid] = bv; ri[tid] = bi;                                         \
    __syncthreads();                                                    \
    for (int s = 128; s > 0; s >>= 1) {                                 \
      if (tid < s) {                                                    \
        double ov = rv[tid + s];                                        \
        int oi = ri[tid + s];                                           \
        if (ov < rv[tid] || (ov == rv[tid] && oi < ri[tid])) {          \
          rv[tid] = ov; ri[tid] = oi;                                   \
        }                                                               \
      }                                                                 \
      __syncthreads();                                                  \
    }                                                                   \
    if (tid == 0 && (R) < nrows) out[list[b0 + (R)]] = ri[0];           \
    __syncthreads();                                                    \
  }

__global__ __launch_bounds__(256) void exact_recheck64(
    const float* __restrict__ x, const float* __restrict__ cent,
    const double* __restrict__ cn64, const int* __restrict__ list,
    const int* __restrict__ counter, int* __restrict__ out) {
  __shared__ __align__(16) float xrow[2][DIM];  // 6 KB
  __shared__ double rv[256];
  __shared__ int ri[256];
  __shared__ double xnorms[2];
  int cnt = counter[0];
  if (cnt > LISTCAP) cnt = LISTCAP;
  int b0 = blockIdx.x * 2;
  if (b0 >= cnt) return;
  int nrows = cnt - b0;
  if (nrows > 2) nrows = 2;
  int tid = threadIdx.x;
  for (int r = 0; r < 2; ++r) {
    int n = list[b0 + (r < nrows ? r : 0)];
    double part = 0.0;
    for (int d = tid; d < DIM; d += 256) {
      float v = x[(size_t)n * DIM + d];
      xrow[r][d] = v;
      part += (double)v * (double)v;
    }
    rv[tid] = part;
    __syncthreads();
    for (int s = 128; s > 0; s >>= 1) {
      if (tid < s) rv[tid] += rv[tid + s];
      __syncthreads();
    }
    if (tid == 0) xnorms[r] = rv[0];
    __syncthreads();
  }

  int k7 = tid + 1792;
  int k7c = (k7 < K_C) ? k7 : (K_C - 1);
  ACCS(0); ACCS(1);
#pragma unroll 2
  for (int d = 0; d < DIM; ++d) {
    const float* cp = cent + (size_t)d * K_C + tid;
    double c0 = cp[0], c1 = cp[256], c2 = cp[512], c3 = cp[768];
    double c4 = cp[1024], c5 = cp[1280], c6 = cp[1536];
    double c7 = cp[k7c - tid];
    double x0 = xrow[0][d], x1 = xrow[1][d];
    FMAS(0, x0); FMAS(1, x1);
  }
  EVAL(0) EVAL(1)
}

extern "C" void kernel_launch(void* const* d_in, const int* in_sizes, int n_in,
                              void* d_out, int out_size, void* d_ws, size_t ws_size,
                              hipStream_t stream) {
  const float* x = (const float*)d_in[0];
  const float* cent = (const float*)d_in[1];
  char* ws = (char*)d_ws;
  f16* cTh = (f16*)ws;
  float* cn = (float*)(ws + OFF_CN);
  float* xn = (float*)(ws + OFF_XN);
  float* pmin = (float*)(ws + OFF_PMIN);
  float* psec = (float*)(ws + OFF_PSEC);
  int* pidx = (int*)(ws + OFF_PIDX);
  int* counter = (int*)(ws + OFF_CNT);
  int* list = (int*)(ws + OFF_LIST);
  double* cn64 = (double*)(ws + OFF_CN64);
  f16* xh = (f16*)(ws + OFF_XH);

  hipMemsetAsync(counter, 0, 4, stream);
  prep_cn<<<64, 256, 0, stream>>>(cent, cn, cn64);
  prep_ct<<<dim3(32, 12), 256, 0, stream>>>(cent, cTh);
  xnorm_prepx<<<N_ROWS / 16, 256, 0, stream>>>(x, xn, xh);
  kmeans_main<<<16384, 256, 0, stream>>>(xh, cTh, cn, xn, pmin, psec, pidx);
  merge_detect<<<N_ROWS / 256, 256, 0, stream>>>(pmin, psec, pidx, (int*)d_out,
                                                 list, counter);
  exact_recheck64<<<LISTCAP / 2, 256, 0, stream>>>(x, cent, cn64, list, counter,
                                                   (int*)d_out);
}